// Round 1
// baseline (213.472 us; speedup 1.0000x reference)
//
#include <hip/hip_runtime.h>
#include <stdint.h>

typedef __attribute__((ext_vector_type(4))) float f32x4;
typedef __attribute__((ext_vector_type(8))) __bf16 bf16v8;
typedef __attribute__((ext_vector_type(8))) unsigned short u16x8;
typedef unsigned short u16;

#define AS1 __attribute__((address_space(1)))
#define AS3 __attribute__((address_space(3)))

__device__ __forceinline__ u16 f2b(float f) {
  union { float f; uint32_t u; } v; v.f = f;
  return (u16)((v.u + 0x7FFFu + ((v.u >> 16) & 1u)) >> 16);
}

__device__ __forceinline__ f32x4 mfma16(bf16v8 a, bf16v8 b, f32x4 c) {
  return __builtin_amdgcn_mfma_f32_16x16x32_bf16(a, b, c, 0, 0, 0);
}

__device__ __forceinline__ void gl_lds16(const void* g, void* l) {
  __builtin_amdgcn_global_load_lds((AS1 void*)g, (AS3 void*)l, 16, 0, 0);
}

// ---------------------------------------------------------------- pack x ----
__global__ __launch_bounds__(256) void pack_x_kernel(
    const float* __restrict__ x, u16* __restrict__ xb, int n8) {
  int i = blockIdx.x * 256 + threadIdx.x;
  if (i >= n8) return;
  const f32x4* p = (const f32x4*)(x + (size_t)i * 8);
  f32x4 a = p[0], b = p[1];
  u16x8 o;
  o[0] = f2b(a[0]); o[1] = f2b(a[1]); o[2] = f2b(a[2]); o[3] = f2b(a[3]);
  o[4] = f2b(b[0]); o[5] = f2b(b[1]); o[6] = f2b(b[2]); o[7] = f2b(b[3]);
  *(u16x8*)(xb + (size_t)i * 8) = o;
}

// --------------------------------------------------------- pack weights ----
// out[n*out_ns + b*out_rs + a] = bf16(in[n*in_ns + a*in_rs + b]) over 64x64 tiles
__global__ __launch_bounds__(256) void pack_w_kernel(
    const float* __restrict__ in, u16* __restrict__ out,
    int in_ns, int in_rs, int out_ns, int out_rs) {
  __shared__ float t[64][65];
  const int n = blockIdx.z;
  const int a0 = blockIdx.x * 64, b0 = blockIdx.y * 64;
  const int c = threadIdx.x & 63, w = threadIdx.x >> 6;
  const float* ip = in + (size_t)n * in_ns;
#pragma unroll
  for (int i = 0; i < 16; ++i) {
    int r = i * 4 + w;
    t[r][c] = ip[(size_t)(a0 + r) * in_rs + (b0 + c)];
  }
  __syncthreads();
  u16* op = out + (size_t)n * out_ns;
#pragma unroll
  for (int i = 0; i < 16; ++i) {
    int r = i * 4 + w;
    op[(size_t)(b0 + r) * out_rs + (a0 + c)] = f2b(t[c][r]);
  }
}

// ------------------------------------------------------------------ GEMM ----
// C[m][col] = (sum_k A[m][k]*Bt[col][k] + bias[col]) * scale
// A: [M][768] bf16, Bt: [768][768] bf16.  Grid (M/128, 6), 256 threads.
template <int OUTF32>
__global__ __launch_bounds__(256, 2) void gemm_bt(
    const u16* __restrict__ A, const u16* __restrict__ Bt,
    void* __restrict__ Cv, const float* __restrict__ bias, float scale) {
  constexpr int K = 768, N = 768;
  __shared__ u16 lA[2][128 * 32];
  __shared__ u16 lB[2][128 * 32];

  const int tid = threadIdx.x;
  const int lane = tid & 63, wid = tid >> 6;
  const int wr = wid >> 1, wc = wid & 1;
  const int g = lane >> 4, l16 = lane & 15;
  const int m0 = blockIdx.x * 128, n0 = blockIdx.y * 128;

  const int srow = tid >> 2;          // tile row for staging (issue 0)
  const int scol = (tid & 3) * 16;    // byte offset within 64B tile row

  f32x4 acc[4][4];
#pragma unroll
  for (int i = 0; i < 4; ++i)
#pragma unroll
    for (int j = 0; j < 4; ++j) acc[i][j] = (f32x4)0.f;

  const char* Ab = (const char*)(A + (size_t)m0 * K);
  const char* Bb = (const char*)(Bt + (size_t)n0 * K);
  char* lAb = (char*)&lA[0][0];
  char* lBb = (char*)&lB[0][0];

#define STAGE(buf, kt)                                                          \
  do {                                                                          \
    int kb = (kt) * 64;                                                         \
    gl_lds16(Ab + (size_t)srow * 1536 + kb + scol,                              \
             lAb + (buf) * 8192 + wid * 1024);                                  \
    gl_lds16(Bb + (size_t)srow * 1536 + kb + scol,                              \
             lBb + (buf) * 8192 + wid * 1024);                                  \
    gl_lds16(Ab + (size_t)(64 + srow) * 1536 + kb + scol,                       \
             lAb + (buf) * 8192 + 4096 + wid * 1024);                           \
    gl_lds16(Bb + (size_t)(64 + srow) * 1536 + kb + scol,                       \
             lBb + (buf) * 8192 + 4096 + wid * 1024);                           \
  } while (0)

  STAGE(0, 0);
  __syncthreads();

  for (int kt = 0; kt < 24; ++kt) {
    const int cur = kt & 1;
    if (kt + 1 < 24) STAGE(cur ^ 1, kt + 1);
    bf16v8 af[4], bfv[4];
#pragma unroll
    for (int i = 0; i < 4; ++i) {
      af[i]  = *(const bf16v8*)&lA[cur][(wr * 64 + i * 16 + l16) * 32 + g * 8];
      bfv[i] = *(const bf16v8*)&lB[cur][(wc * 64 + i * 16 + l16) * 32 + g * 8];
    }
#pragma unroll
    for (int i = 0; i < 4; ++i)
#pragma unroll
      for (int j = 0; j < 4; ++j)
        acc[i][j] = mfma16(af[i], bfv[j], acc[i][j]);
    __syncthreads();
  }
#undef STAGE

  const int row0 = m0 + wr * 64, col0 = n0 + wc * 64;
#pragma unroll
  for (int j = 0; j < 4; ++j) {
    const int col = col0 + j * 16 + l16;
    const float bv = bias[col];
#pragma unroll
    for (int i = 0; i < 4; ++i) {
#pragma unroll
      for (int r = 0; r < 4; ++r) {
        const int row = row0 + i * 16 + g * 4 + r;
        const float v = (acc[i][j][r] + bv) * scale;
        if (OUTF32) ((float*)Cv)[(size_t)row * N + col] = v;
        else        ((u16*)Cv)[(size_t)row * N + col] = f2b(v);
      }
    }
  }
}

// ----------------------------------------------------------- flash attn ----
// Q,K,V,Z: [B*S][768] bf16 with head n at cols n*64..n*64+63.
// Grid (8 qtiles, 96 heads), 256 threads; wave w owns q-rows q0+32w..+31.
__global__ __launch_bounds__(256, 2) void flash_kernel(
    const u16* __restrict__ Q, const u16* __restrict__ K,
    const u16* __restrict__ V, u16* __restrict__ Z) {
  __shared__ u16 lK[2][32 * 72];    // [kv][h], padded row 72
  __shared__ u16 lVt[2][64 * 40];   // [h][kv], padded row 40
  __shared__ u16 lP[4][32 * 40];    // per-wave P, [q][kv], padded row 40

  const int tid = threadIdx.x;
  const int lane = tid & 63, wid = tid >> 6;
  const int g = lane >> 4, l16 = lane & 15;
  const int head = blockIdx.y;
  const int b = head / 12, n = head % 12;
  const int q0 = blockIdx.x * 128;
  const int qw = q0 + wid * 32;

  const size_t hb = (size_t)b * 1024 * 768 + (size_t)n * 64;
  const u16* Qh = Q + hb;
  const u16* Kh = K + hb;
  const u16* Vh = V + hb;
  u16* Zh = Z + hb;

  // Q fragments (Q already scaled by 1/8 in projection)
  bf16v8 qf[2][2];
#pragma unroll
  for (int mt = 0; mt < 2; ++mt)
#pragma unroll
    for (int kt = 0; kt < 2; ++kt)
      qf[mt][kt] = *(const bf16v8*)(Qh + (size_t)(qw + mt * 16 + l16) * 768 +
                                    kt * 32 + g * 8);

  f32x4 po[2][4];
  float mrow[2][4], lrow[2][4];
#pragma unroll
  for (int mt = 0; mt < 2; ++mt)
#pragma unroll
    for (int r = 0; r < 4; ++r) {
      mrow[mt][r] = -1e30f; lrow[mt][r] = 0.f;
#pragma unroll
      for (int ht = 0; ht < 4; ++ht) po[mt][ht] = (f32x4)0.f;
    }

  const int nch = (q0 >> 5) + 4;
  const int krow = tid >> 3, kcol = (tid & 7) * 8;   // K staging: [32][64]
  const int vrow = tid & 31, vcol = (tid >> 5) * 8;  // V staging: col kv, 8 h's

  u16x8 kreg, vreg;
#define LOADC(c)                                                              \
  do {                                                                        \
    int kv0_ = (c) * 32;                                                      \
    kreg = *(const u16x8*)(Kh + (size_t)(kv0_ + krow) * 768 + kcol);          \
    vreg = *(const u16x8*)(Vh + (size_t)(kv0_ + vrow) * 768 + vcol);          \
  } while (0)
#define WRITEC(buf)                                                           \
  do {                                                                        \
    *(u16x8*)&lK[buf][krow * 72 + kcol] = kreg;                               \
    _Pragma("unroll") for (int j = 0; j < 8; ++j)                             \
        lVt[buf][(vcol + j) * 40 + vrow] = vreg[j];                           \
  } while (0)

  LOADC(0);
  WRITEC(0);
  __syncthreads();

  for (int c = 0; c < nch; ++c) {
    const int cur = c & 1;
    const int kv0 = c * 32;
    if (c + 1 < nch) LOADC(c + 1);

    if (kv0 < qw + 32) {
      bf16v8 kf[2][2];
#pragma unroll
      for (int nt = 0; nt < 2; ++nt)
#pragma unroll
        for (int kt = 0; kt < 2; ++kt)
          kf[nt][kt] = *(const bf16v8*)&lK[cur][(nt * 16 + l16) * 72 +
                                               kt * 32 + g * 8];
      f32x4 s[2][2];
#pragma unroll
      for (int mt = 0; mt < 2; ++mt)
#pragma unroll
        for (int nt = 0; nt < 2; ++nt) {
          s[mt][nt] = (f32x4)0.f;
#pragma unroll
          for (int kt = 0; kt < 2; ++kt)
            s[mt][nt] = mfma16(qf[mt][kt], kf[nt][kt], s[mt][nt]);
        }
      if (kv0 + 31 > qw) {  // boundary chunk: causal mask kv > q
#pragma unroll
        for (int mt = 0; mt < 2; ++mt)
#pragma unroll
          for (int nt = 0; nt < 2; ++nt) {
            const int kv = kv0 + nt * 16 + l16;
#pragma unroll
            for (int r = 0; r < 4; ++r) {
              const int q = qw + mt * 16 + g * 4 + r;
              if (kv > q) s[mt][nt][r] = -1e30f;
            }
          }
      }
      // online softmax per q-row (rows live in 16-lane groups)
#pragma unroll
      for (int mt = 0; mt < 2; ++mt) {
#pragma unroll
        for (int r = 0; r < 4; ++r) {
          float cm = fmaxf(s[mt][0][r], s[mt][1][r]);
          cm = fmaxf(cm, __shfl_xor(cm, 1));
          cm = fmaxf(cm, __shfl_xor(cm, 2));
          cm = fmaxf(cm, __shfl_xor(cm, 4));
          cm = fmaxf(cm, __shfl_xor(cm, 8));
          const float mnew = fmaxf(mrow[mt][r], cm);
          const float scl = __expf(mrow[mt][r] - mnew);
          mrow[mt][r] = mnew;
          const float p0 = __expf(s[mt][0][r] - mnew);
          const float p1 = __expf(s[mt][1][r] - mnew);
          s[mt][0][r] = p0; s[mt][1][r] = p1;
          float rs = p0 + p1;
          rs += __shfl_xor(rs, 1);
          rs += __shfl_xor(rs, 2);
          rs += __shfl_xor(rs, 4);
          rs += __shfl_xor(rs, 8);
          lrow[mt][r] = lrow[mt][r] * scl + rs;
#pragma unroll
          for (int ht = 0; ht < 4; ++ht) po[mt][ht][r] *= scl;
        }
      }
      // P -> per-wave LDS (re-layout for PV A-fragments)
#pragma unroll
      for (int mt = 0; mt < 2; ++mt)
#pragma unroll
        for (int nt = 0; nt < 2; ++nt)
#pragma unroll
          for (int r = 0; r < 4; ++r)
            lP[wid][(mt * 16 + g * 4 + r) * 40 + nt * 16 + l16] =
                f2b(s[mt][nt][r]);
      bf16v8 pa[2];
#pragma unroll
      for (int mt = 0; mt < 2; ++mt)
        pa[mt] = *(const bf16v8*)&lP[wid][(mt * 16 + l16) * 40 + g * 8];
#pragma unroll
      for (int ht = 0; ht < 4; ++ht) {
        bf16v8 vf = *(const bf16v8*)&lVt[cur][(ht * 16 + l16) * 40 + g * 8];
#pragma unroll
        for (int mt = 0; mt < 2; ++mt)
          po[mt][ht] = mfma16(pa[mt], vf, po[mt][ht]);
      }
    }
    if (c + 1 < nch) WRITEC(cur ^ 1);
    __syncthreads();
  }
#undef LOADC
#undef WRITEC

#pragma unroll
  for (int mt = 0; mt < 2; ++mt)
#pragma unroll
    for (int ht = 0; ht < 4; ++ht)
#pragma unroll
      for (int r = 0; r < 4; ++r) {
        const int q = qw + mt * 16 + g * 4 + r;
        const int h = ht * 16 + l16;
        Zh[(size_t)q * 768 + h] = f2b(po[mt][ht][r] / lrow[mt][r]);
      }
}

// ---------------------------------------------------------------- launch ----
extern "C" void kernel_launch(void* const* d_in, const int* in_sizes, int n_in,
                              void* d_out, int out_size, void* d_ws,
                              size_t ws_size, hipStream_t stream) {
  const float* x  = (const float*)d_in[0];
  const float* wq = (const float*)d_in[1];
  const float* wk = (const float*)d_in[2];
  const float* wv = (const float*)d_in[3];
  const float* wo = (const float*)d_in[4];
  const float* bq = (const float*)d_in[5];
  const float* bk = (const float*)d_in[6];
  const float* bv = (const float*)d_in[7];
  const float* bo = (const float*)d_in[8];
  float* out = (float*)d_out;

  char* ws = (char*)d_ws;
  u16* Xb  = (u16*)ws; ws += 12582912;   // [8192][768] bf16
  u16* WqT = (u16*)ws; ws += 1179648;    // [768][768] bf16 (B^T layout)
  u16* WkT = (u16*)ws; ws += 1179648;
  u16* WvT = (u16*)ws; ws += 1179648;
  u16* WoT = (u16*)ws; ws += 1179648;
  u16* Qb  = (u16*)ws; ws += 12582912;
  u16* Kb  = (u16*)ws; ws += 12582912;
  u16* Vb  = (u16*)ws; ws += 12582912;
  u16* Zb  = (u16*)ws; ws += 12582912;

  pack_x_kernel<<<3072, 256, 0, stream>>>(x, Xb, 786432);
  // W_{Q,K,V}: [12][768][64] -> WT[(n*64+h)][d]
  pack_w_kernel<<<dim3(12, 1, 12), 256, 0, stream>>>(wq, WqT, 49152, 64, 49152, 768);
  pack_w_kernel<<<dim3(12, 1, 12), 256, 0, stream>>>(wk, WkT, 49152, 64, 49152, 768);
  pack_w_kernel<<<dim3(12, 1, 12), 256, 0, stream>>>(wv, WvT, 49152, 64, 49152, 768);
  // W_O: [12][64][768] -> WoT[e][(n*64+h)]
  pack_w_kernel<<<dim3(1, 12, 12), 256, 0, stream>>>(wo, WoT, 49152, 768, 64, 768);

  dim3 gg(64, 6);
  gemm_bt<0><<<gg, 256, 0, stream>>>(Xb, WqT, Qb, bq, 0.125f);  // (Q+b)/sqrt(64)
  gemm_bt<0><<<gg, 256, 0, stream>>>(Xb, WkT, Kb, bk, 1.0f);
  gemm_bt<0><<<gg, 256, 0, stream>>>(Xb, WvT, Vb, bv, 1.0f);

  flash_kernel<<<dim3(8, 96), 256, 0, stream>>>(Qb, Kb, Vb, Zb);

  gemm_bt<1><<<gg, 256, 0, stream>>>(Zb, WoT, out, bo, 1.0f);
}

// Round 3
// 186.547 us; speedup vs baseline: 1.1443x; 1.1443x over previous
//
#include <hip/hip_runtime.h>
#include <stdint.h>

typedef __attribute__((ext_vector_type(4))) float f32x4;
typedef __attribute__((ext_vector_type(8))) __bf16 bf16v8;
typedef __attribute__((ext_vector_type(8))) unsigned short u16x8;
typedef __attribute__((ext_vector_type(4))) unsigned short u16x4;
typedef unsigned short u16;

#define AS1 __attribute__((address_space(1)))
#define AS3 __attribute__((address_space(3)))

__device__ __forceinline__ u16 f2b(float f) {
  union { float f; uint32_t u; } v; v.f = f;
  return (u16)((v.u + 0x7FFFu + ((v.u >> 16) & 1u)) >> 16);
}

__device__ __forceinline__ f32x4 mfma16(bf16v8 a, bf16v8 b, f32x4 c) {
  return __builtin_amdgcn_mfma_f32_16x16x32_bf16(a, b, c, 0, 0, 0);
}

__device__ __forceinline__ void gl_lds16(const void* g, void* l) {
  __builtin_amdgcn_global_load_lds((AS1 void*)g, (AS3 void*)l, 16, 0, 0);
}

// ---------------------------------------------------------------- pack x ----
__global__ __launch_bounds__(256) void pack_x_kernel(
    const float* __restrict__ x, u16* __restrict__ xb, int n8) {
  int i = blockIdx.x * 256 + threadIdx.x;
  if (i >= n8) return;
  const f32x4* p = (const f32x4*)(x + (size_t)i * 8);
  f32x4 a = p[0], b = p[1];
  u16x8 o;
  o[0] = f2b(a[0]); o[1] = f2b(a[1]); o[2] = f2b(a[2]); o[3] = f2b(a[3]);
  o[4] = f2b(b[0]); o[5] = f2b(b[1]); o[6] = f2b(b[2]); o[7] = f2b(b[3]);
  *(u16x8*)(xb + (size_t)i * 8) = o;
}

// --------------------------------------------------------- pack weights ----
// out[n*out_ns + b*out_rs + a] = bf16(in[n*in_ns + a*in_rs + b]) over 64x64 tiles
__global__ __launch_bounds__(256) void pack_w_kernel(
    const float* __restrict__ in, u16* __restrict__ out,
    int in_ns, int in_rs, int out_ns, int out_rs) {
  __shared__ float t[64][65];
  const int n = blockIdx.z;
  const int a0 = blockIdx.x * 64, b0 = blockIdx.y * 64;
  const int c = threadIdx.x & 63, w = threadIdx.x >> 6;
  const float* ip = in + (size_t)n * in_ns;
#pragma unroll
  for (int i = 0; i < 16; ++i) {
    int r = i * 4 + w;
    t[r][c] = ip[(size_t)(a0 + r) * in_rs + (b0 + c)];
  }
  __syncthreads();
  u16* op = out + (size_t)n * out_ns;
#pragma unroll
  for (int i = 0; i < 16; ++i) {
    int r = i * 4 + w;
    op[(size_t)(b0 + r) * out_rs + (a0 + c)] = f2b(t[c][r]);
  }
}

// ------------------------------------------------------------------ GEMM ----
// C[m][col] = (sum_k A[m][k]*Bt[col][k] + bias[BIASROW? m : col]) * scale
// A: [M][768] bf16, Bt: [Ncols][768] bf16.  Grid (M/128, Ncols/128), 256 thr.
template <int OUTF32, int BIASROW>
__global__ __launch_bounds__(256, 2) void gemm_bt(
    const u16* __restrict__ A, const u16* __restrict__ Bt,
    void* __restrict__ Cv, const float* __restrict__ bias, float scale, int N) {
  constexpr int K = 768;
  __shared__ u16 lA[2][128 * 32];
  __shared__ u16 lB[2][128 * 32];

  const int tid = threadIdx.x;
  const int lane = tid & 63, wid = tid >> 6;
  const int wr = wid >> 1, wc = wid & 1;
  const int g = lane >> 4, l16 = lane & 15;
  const int m0 = blockIdx.x * 128, n0 = blockIdx.y * 128;

  const int srow = tid >> 2;          // tile row for staging
  const int scol = (tid & 3) * 16;    // byte offset within 64B tile row

  f32x4 acc[4][4];
#pragma unroll
  for (int i = 0; i < 4; ++i)
#pragma unroll
    for (int j = 0; j < 4; ++j) acc[i][j] = (f32x4)0.f;

  const char* Ab = (const char*)(A + (size_t)m0 * K);
  const char* Bb = (const char*)(Bt + (size_t)n0 * K);
  char* lAb = (char*)&lA[0][0];
  char* lBb = (char*)&lB[0][0];

#define STAGE(buf, kt)                                                          \
  do {                                                                          \
    int kb = (kt) * 64;                                                         \
    gl_lds16(Ab + (size_t)srow * 1536 + kb + scol,                              \
             lAb + (buf) * 8192 + wid * 1024);                                  \
    gl_lds16(Bb + (size_t)srow * 1536 + kb + scol,                              \
             lBb + (buf) * 8192 + wid * 1024);                                  \
    gl_lds16(Ab + (size_t)(64 + srow) * 1536 + kb + scol,                       \
             lAb + (buf) * 8192 + 4096 + wid * 1024);                           \
    gl_lds16(Bb + (size_t)(64 + srow) * 1536 + kb + scol,                       \
             lBb + (buf) * 8192 + 4096 + wid * 1024);                           \
  } while (0)

  STAGE(0, 0);
  __syncthreads();

  for (int kt = 0; kt < 24; ++kt) {
    const int cur = kt & 1;
    if (kt + 1 < 24) STAGE(cur ^ 1, kt + 1);
    bf16v8 af[4], bfv[4];
#pragma unroll
    for (int i = 0; i < 4; ++i) {
      af[i]  = *(const bf16v8*)&lA[cur][(wr * 64 + i * 16 + l16) * 32 + g * 8];
      bfv[i] = *(const bf16v8*)&lB[cur][(wc * 64 + i * 16 + l16) * 32 + g * 8];
    }
#pragma unroll
    for (int i = 0; i < 4; ++i)
#pragma unroll
      for (int j = 0; j < 4; ++j)
        acc[i][j] = mfma16(af[i], bfv[j], acc[i][j]);
    __syncthreads();
  }
#undef STAGE

  const int row0 = m0 + wr * 64, col0 = n0 + wc * 64;
#pragma unroll
  for (int j = 0; j < 4; ++j) {
    const int col = col0 + j * 16 + l16;
    const float bcol = BIASROW ? 0.f : bias[col];
#pragma unroll
    for (int i = 0; i < 4; ++i) {
#pragma unroll
      for (int r = 0; r < 4; ++r) {
        const int row = row0 + i * 16 + g * 4 + r;
        const float bv = BIASROW ? bias[row] : bcol;
        const float v = (acc[i][j][r] + bv) * scale;
        if (OUTF32) ((float*)Cv)[(size_t)row * N + col] = v;
        else        ((u16*)Cv)[(size_t)row * N + col] = f2b(v);
      }
    }
  }
}

// ----------------------------------------------------------- flash attn ----
// Q,K: [B*S][768] bf16 (head n at cols n*64..); Vt: [768][8192] bf16
// (row n*64+h, col b*1024+s).  Z: [B*S][768] bf16.
// Grid (8, 96), 256 threads; wave w handles q-tile (blockIdx.x + 8w) of 32
// rows.  Waves fully independent: no __syncthreads; LDS only for per-wave
// P re-layout.  Swapped QK^T: S^T = mfma(K, Q) so softmax is lane-local.
__global__ __launch_bounds__(256) void flash2_kernel(
    const u16* __restrict__ Q, const u16* __restrict__ K,
    const u16* __restrict__ Vt, u16* __restrict__ Z) {
  __shared__ u16 lP[4][32 * 72];
  const int tid = threadIdx.x;
  const int lane = tid & 63, wid = tid >> 6;
  const int g = lane >> 4, l16 = lane & 15;
  const int head = blockIdx.y;
  const int b = head / 12, n = head % 12;
  const int qtile = (int)blockIdx.x + wid * 8;  // 0..31
  const int qw = qtile * 32;

  const size_t hb = (size_t)b * 1024 * 768 + (size_t)n * 64;
  const u16* Qh = Q + hb;
  const u16* Kh = K + hb;
  const u16* Vh = Vt + (size_t)n * 64 * 8192 + (size_t)b * 1024;
  u16* Zh = Z + hb;
  u16* myP = &lP[wid][0];

  // Q fragments (B-operand): Q[qw + qt*16 + l16][kk*32 + g*8 ..]
  bf16v8 qf[2][2];
#pragma unroll
  for (int qt = 0; qt < 2; ++qt)
#pragma unroll
    for (int kk = 0; kk < 2; ++kk)
      qf[qt][kk] = *(const bf16v8*)(Qh + (size_t)(qw + qt * 16 + l16) * 768 +
                                    kk * 32 + g * 8);

  f32x4 po[2][4];
#pragma unroll
  for (int qt = 0; qt < 2; ++qt)
#pragma unroll
    for (int ht = 0; ht < 4; ++ht) po[qt][ht] = (f32x4)0.f;
  float m[2] = {-3e38f, -3e38f};
  float l[2] = {0.f, 0.f};

  const int nch = (qw + 95) >> 6;
  for (int c = 0; c < nch; ++c) {
    const int kv0 = c * 64;
    // K fragments (A-operand) straight from global (L2-resident)
    bf16v8 kf[4][2];
#pragma unroll
    for (int kvt = 0; kvt < 4; ++kvt)
#pragma unroll
      for (int kk = 0; kk < 2; ++kk)
        kf[kvt][kk] = *(const bf16v8*)(Kh +
            (size_t)(kv0 + kvt * 16 + l16) * 768 + kk * 32 + g * 8);
    // S^T[kv][q]
    f32x4 s[4][2];
#pragma unroll
    for (int kvt = 0; kvt < 4; ++kvt)
#pragma unroll
      for (int qt = 0; qt < 2; ++qt) {
        f32x4 a = (f32x4)0.f;
        a = mfma16(kf[kvt][0], qf[qt][0], a);
        a = mfma16(kf[kvt][1], qf[qt][1], a);
        s[kvt][qt] = a;
      }
    // V^T fragments (B-operand) — issued here so latency hides under softmax
    bf16v8 vf[4][2];
#pragma unroll
    for (int ht = 0; ht < 4; ++ht)
#pragma unroll
      for (int kk = 0; kk < 2; ++kk)
        vf[ht][kk] = *(const bf16v8*)(Vh + (size_t)(ht * 16 + l16) * 8192 +
                                      kv0 + kk * 32 + g * 8);
    if (c == nch - 1) {  // causal mask, only ever needed on the last chunk
#pragma unroll
      for (int kvt = 0; kvt < 4; ++kvt) {
        const int kv = kv0 + kvt * 16 + g * 4;
#pragma unroll
        for (int qt = 0; qt < 2; ++qt) {
          const int q = qw + qt * 16 + l16;
#pragma unroll
          for (int r = 0; r < 4; ++r)
            if (kv + r > q) s[kvt][qt][r] = -3e38f;
        }
      }
    }
    // online softmax: row q = l16 is lane-local over kv (16 regs + 2 shfl)
#pragma unroll
    for (int qt = 0; qt < 2; ++qt) {
      float cm = s[0][qt][0];
#pragma unroll
      for (int kvt = 0; kvt < 4; ++kvt)
#pragma unroll
        for (int r = 0; r < 4; ++r) cm = fmaxf(cm, s[kvt][qt][r]);
      cm = fmaxf(cm, __shfl_xor(cm, 16));
      cm = fmaxf(cm, __shfl_xor(cm, 32));
      const float mn = fmaxf(m[qt], cm);
      const float scl = __expf(m[qt] - mn);
      m[qt] = mn;
      float rs = 0.f;
#pragma unroll
      for (int kvt = 0; kvt < 4; ++kvt) {
        u16x4 pw;
#pragma unroll
        for (int r = 0; r < 4; ++r) {
          const float p = __expf(s[kvt][qt][r] - mn);
          rs += p;
          pw[r] = f2b(p);
        }
        // P[q][kv]: row q = qt*16+l16, cols kvt*16+g*4 .. +3 (b64 write)
        *(u16x4*)&myP[(qt * 16 + l16) * 72 + kvt * 16 + g * 4] = pw;
      }
      rs += __shfl_xor(rs, 16);
      rs += __shfl_xor(rs, 32);
      l[qt] = l[qt] * scl + rs;
      // rescale po: its q = g*4+r lives at lane l16' = g*4+r
#pragma unroll
      for (int r = 0; r < 4; ++r) {
        const float sr = __shfl(scl, g * 4 + r);
#pragma unroll
        for (int ht = 0; ht < 4; ++ht) po[qt][ht][r] *= sr;
      }
    }
    // P fragments (A-operand) from wave-private LDS
    bf16v8 pa[2][2];
#pragma unroll
    for (int mt = 0; mt < 2; ++mt)
#pragma unroll
      for (int kk = 0; kk < 2; ++kk)
        pa[mt][kk] = *(const bf16v8*)&myP[(mt * 16 + l16) * 72 +
                                          kk * 32 + g * 8];
#pragma unroll
    for (int ht = 0; ht < 4; ++ht)
#pragma unroll
      for (int mt = 0; mt < 2; ++mt) {
        po[mt][ht] = mfma16(pa[mt][0], vf[ht][0], po[mt][ht]);
        po[mt][ht] = mfma16(pa[mt][1], vf[ht][1], po[mt][ht]);
      }
  }
  // epilogue: broadcast l to accumulator layout, divide, store
#pragma unroll
  for (int qt = 0; qt < 2; ++qt) {
#pragma unroll
    for (int r = 0; r < 4; ++r) {
      const float lr = __shfl(l[qt], g * 4 + r);
      const float inv = 1.f / lr;
      const int q = qw + qt * 16 + g * 4 + r;
#pragma unroll
      for (int ht = 0; ht < 4; ++ht)
        Zh[(size_t)q * 768 + ht * 16 + l16] = f2b(po[qt][ht][r] * inv);
    }
  }
}

// ---------------------------------------------------------------- launch ----
extern "C" void kernel_launch(void* const* d_in, const int* in_sizes, int n_in,
                              void* d_out, int out_size, void* d_ws,
                              size_t ws_size, hipStream_t stream) {
  const float* x  = (const float*)d_in[0];
  const float* wq = (const float*)d_in[1];
  const float* wk = (const float*)d_in[2];
  const float* wv = (const float*)d_in[3];
  const float* wo = (const float*)d_in[4];
  const float* bq = (const float*)d_in[5];
  const float* bk = (const float*)d_in[6];
  const float* bv = (const float*)d_in[7];
  const float* bo = (const float*)d_in[8];
  float* out = (float*)d_out;

  char* ws = (char*)d_ws;
  u16* Xb  = (u16*)ws; ws += 12582912;   // [8192][768] bf16
  u16* WqT = (u16*)ws; ws += 1179648;    // [768][768] bf16 (B^T layout)
  u16* WkT = (u16*)ws; ws += 1179648;
  u16* WvT = (u16*)ws; ws += 1179648;
  u16* WoT = (u16*)ws; ws += 1179648;
  u16* Qb  = (u16*)ws; ws += 12582912;   // [8192][768]
  u16* Kb  = (u16*)ws; ws += 12582912;   // [8192][768]
  u16* Vtb = (u16*)ws; ws += 12582912;   // [768][8192]  (V transposed)
  u16* Zb  = (u16*)ws; ws += 12582912;   // [8192][768]

  pack_x_kernel<<<3072, 256, 0, stream>>>(x, Xb, 786432);
  // W_{Q,K,V}: [12][768][64] -> WT[(n*64+h)][d]
  pack_w_kernel<<<dim3(12, 1, 12), 256, 0, stream>>>(wq, WqT, 49152, 64, 49152, 768);
  pack_w_kernel<<<dim3(12, 1, 12), 256, 0, stream>>>(wk, WkT, 49152, 64, 49152, 768);
  pack_w_kernel<<<dim3(12, 1, 12), 256, 0, stream>>>(wv, WvT, 49152, 64, 49152, 768);
  // W_O: [12][64][768] -> WoT[e][(n*64+h)]
  pack_w_kernel<<<dim3(1, 12, 12), 256, 0, stream>>>(wo, WoT, 49152, 768, 64, 768);

  gemm_bt<0, 0><<<dim3(64, 6), 256, 0, stream>>>(Xb, WqT, Qb, bq, 0.125f, 768);
  gemm_bt<0, 0><<<dim3(64, 6), 256, 0, stream>>>(Xb, WkT, Kb, bk, 1.0f, 768);
  // V^T = (Wv^T) · X^T directly: A = WvT [768][768], Bt = Xb [8192][768]
  gemm_bt<0, 1><<<dim3(6, 64), 256, 0, stream>>>(WvT, Xb, Vtb, bv, 1.0f, 8192);

  flash2_kernel<<<dim3(8, 96), 256, 0, stream>>>(Qb, Kb, Vtb, Zb);

  gemm_bt<1, 0><<<dim3(64, 6), 256, 0, stream>>>(Zb, WoT, out, bo, 1.0f, 768);
}

// Round 4
// 152.783 us; speedup vs baseline: 1.3972x; 1.2210x over previous
//
#include <hip/hip_runtime.h>
#include <stdint.h>

typedef __attribute__((ext_vector_type(4))) float f32x4;
typedef __attribute__((ext_vector_type(8))) __bf16 bf16v8;
typedef __attribute__((ext_vector_type(8))) unsigned short u16x8;
typedef __attribute__((ext_vector_type(4))) unsigned short u16x4;
typedef unsigned short u16;

#define AS1 __attribute__((address_space(1)))
#define AS3 __attribute__((address_space(3)))

__device__ __forceinline__ u16 f2b(float f) {
  union { float f; uint32_t u; } v; v.f = f;
  return (u16)((v.u + 0x7FFFu + ((v.u >> 16) & 1u)) >> 16);
}

__device__ __forceinline__ f32x4 mfma16(bf16v8 a, bf16v8 b, f32x4 c) {
  return __builtin_amdgcn_mfma_f32_16x16x32_bf16(a, b, c, 0, 0, 0);
}

__device__ __forceinline__ void gl_lds16(const void* g, void* l) {
  __builtin_amdgcn_global_load_lds((AS1 void*)g, (AS3 void*)l, 16, 0, 0);
}

// ---------------------------------------------------------------- pack x ----
__global__ __launch_bounds__(256) void pack_x_kernel(
    const float* __restrict__ x, u16* __restrict__ xb, int n8) {
  int i = blockIdx.x * 256 + threadIdx.x;
  if (i >= n8) return;
  const f32x4* p = (const f32x4*)(x + (size_t)i * 8);
  f32x4 a = p[0], b = p[1];
  u16x8 o;
  o[0] = f2b(a[0]); o[1] = f2b(a[1]); o[2] = f2b(a[2]); o[3] = f2b(a[3]);
  o[4] = f2b(b[0]); o[5] = f2b(b[1]); o[6] = f2b(b[2]); o[7] = f2b(b[3]);
  *(u16x8*)(xb + (size_t)i * 8) = o;
}

// --------------------------------------------------------- pack weights ----
__global__ __launch_bounds__(256) void pack_w_kernel(
    const float* __restrict__ in, u16* __restrict__ out,
    int in_ns, int in_rs, int out_ns, int out_rs) {
  __shared__ float t[64][65];
  const int n = blockIdx.z;
  const int a0 = blockIdx.x * 64, b0 = blockIdx.y * 64;
  const int c = threadIdx.x & 63, w = threadIdx.x >> 6;
  const float* ip = in + (size_t)n * in_ns;
#pragma unroll
  for (int i = 0; i < 16; ++i) {
    int r = i * 4 + w;
    t[r][c] = ip[(size_t)(a0 + r) * in_rs + (b0 + c)];
  }
  __syncthreads();
  u16* op = out + (size_t)n * out_ns;
#pragma unroll
  for (int i = 0; i < 16; ++i) {
    int r = i * 4 + w;
    op[(size_t)(b0 + r) * out_rs + (a0 + c)] = f2b(t[c][r]);
  }
}

// ------------------------------------------------------------------ GEMM ----
template <int OUTF32, int BIASROW>
__global__ __launch_bounds__(256, 2) void gemm_bt(
    const u16* __restrict__ A, const u16* __restrict__ Bt,
    void* __restrict__ Cv, const float* __restrict__ bias, float scale, int N) {
  constexpr int K = 768;
  __shared__ u16 lA[2][128 * 32];
  __shared__ u16 lB[2][128 * 32];

  const int tid = threadIdx.x;
  const int lane = tid & 63, wid = tid >> 6;
  const int wr = wid >> 1, wc = wid & 1;
  const int g = lane >> 4, l16 = lane & 15;
  const int m0 = blockIdx.x * 128, n0 = blockIdx.y * 128;

  const int srow = tid >> 2;
  const int scol = (tid & 3) * 16;

  f32x4 acc[4][4];
#pragma unroll
  for (int i = 0; i < 4; ++i)
#pragma unroll
    for (int j = 0; j < 4; ++j) acc[i][j] = (f32x4)0.f;

  const char* Ab = (const char*)(A + (size_t)m0 * K);
  const char* Bb = (const char*)(Bt + (size_t)n0 * K);
  char* lAb = (char*)&lA[0][0];
  char* lBb = (char*)&lB[0][0];

#define STAGE(buf, kt)                                                          \
  do {                                                                          \
    int kb = (kt) * 64;                                                         \
    gl_lds16(Ab + (size_t)srow * 1536 + kb + scol,                              \
             lAb + (buf) * 8192 + wid * 1024);                                  \
    gl_lds16(Bb + (size_t)srow * 1536 + kb + scol,                              \
             lBb + (buf) * 8192 + wid * 1024);                                  \
    gl_lds16(Ab + (size_t)(64 + srow) * 1536 + kb + scol,                       \
             lAb + (buf) * 8192 + 4096 + wid * 1024);                           \
    gl_lds16(Bb + (size_t)(64 + srow) * 1536 + kb + scol,                       \
             lBb + (buf) * 8192 + 4096 + wid * 1024);                           \
  } while (0)

  STAGE(0, 0);
  __syncthreads();

  for (int kt = 0; kt < 24; ++kt) {
    const int cur = kt & 1;
    if (kt + 1 < 24) STAGE(cur ^ 1, kt + 1);
    bf16v8 af[4], bfv[4];
#pragma unroll
    for (int i = 0; i < 4; ++i) {
      af[i]  = *(const bf16v8*)&lA[cur][(wr * 64 + i * 16 + l16) * 32 + g * 8];
      bfv[i] = *(const bf16v8*)&lB[cur][(wc * 64 + i * 16 + l16) * 32 + g * 8];
    }
#pragma unroll
    for (int i = 0; i < 4; ++i)
#pragma unroll
      for (int j = 0; j < 4; ++j)
        acc[i][j] = mfma16(af[i], bfv[j], acc[i][j]);
    __syncthreads();
  }
#undef STAGE

  const int row0 = m0 + wr * 64, col0 = n0 + wc * 64;
#pragma unroll
  for (int j = 0; j < 4; ++j) {
    const int col = col0 + j * 16 + l16;
    const float bcol = BIASROW ? 0.f : bias[col];
#pragma unroll
    for (int i = 0; i < 4; ++i) {
#pragma unroll
      for (int r = 0; r < 4; ++r) {
        const int row = row0 + i * 16 + g * 4 + r;
        const float bv = BIASROW ? bias[row] : bcol;
        const float v = (acc[i][j][r] + bv) * scale;
        if (OUTF32) ((float*)Cv)[(size_t)row * N + col] = v;
        else        ((u16*)Cv)[(size_t)row * N + col] = f2b(v);
      }
    }
  }
}

// ----------------------------------------------------------- flash attn ----
// Q,K: [B*S][768] bf16 (head n at cols n*64..); Vt: [768][8192] bf16
// (row n*64+h, col b*1024+s).  Z: [B*S][768] bf16.
// Grid: 768 linear blocks, 256 threads.  Block id remapped so all 8 q-blocks
// of a head share id%8 -> same XCD (L2 working set 12 heads x 256KB = 3MB).
// Block handles 128 q-rows (wave w: rows qblock+32w..+31); K/V chunks of 64
// staged cooperatively in LDS via global_load_lds (linear dest, XOR-swizzled
// source; reads use the same XOR involution -> conflict-free b128).
// Swapped QK^T: S^T = mfma(K, Q) so softmax is lane-local.
__global__ __launch_bounds__(256, 3) void flash3_kernel(
    const u16* __restrict__ Q, const u16* __restrict__ K,
    const u16* __restrict__ Vt, u16* __restrict__ Z) {
  __shared__ u16 lK[2][64 * 64];   // [kv][h]  (swizzled 16B slots)
  __shared__ u16 lV[2][64 * 64];   // [h][kv]  (swizzled 16B slots)
  __shared__ u16 lP[4][32 * 72];   // per-wave P relayout

  const int tid = threadIdx.x;
  const int lane = tid & 63, wid = tid >> 6;
  const int g = lane >> 4, l16 = lane & 15;

  // id remap: head%8 == hid%8 (XCD grouping); long blocks (q=7) first
  const int hid = blockIdx.x;
  const int xs = hid & 7;
  const int rest = hid >> 3;                 // 0..95
  const int q = 7 - (rest & 7);
  const int head = xs + ((rest >> 3) << 3);  // 0..95, head%8==xs
  const int b = head / 12, n = head % 12;

  const int qblock = q << 7;
  const int qw = qblock + (wid << 5);
  const int nch = 2 * q + 2;

  const size_t hb = (size_t)b * 1024 * 768 + (size_t)n * 64;
  const u16* Qh = Q + hb;
  const u16* Kh = K + hb;
  const u16* Vh = Vt + (size_t)n * 64 * 8192 + (size_t)b * 1024;
  u16* Zh = Z + hb;
  u16* myP = &lP[wid][0];

  // staging decomposition: lane -> (row-in-8, 16B slot), source pre-swizzled
  const int srow8 = lane >> 3;
  const int sslot = lane & 7;
  const int scol = ((sslot ^ srow8) << 4);   // swizzled byte col in [0,128)

#define FSTAGE(buf, c)                                                        \
  do {                                                                        \
    const int kv0_ = (c) << 6;                                                \
    const char* kb_ = (const char*)Kh + (size_t)(kv0_ + (wid << 4)) * 1536;   \
    const char* vb_ = (const char*)Vh + (size_t)(wid << 4) * 16384 +          \
                      (size_t)kv0_ * 2;                                       \
    gl_lds16(kb_ + (size_t)srow8 * 1536 + scol,                               \
             (char*)&lK[buf][0] + (wid << 11));                               \
    gl_lds16(kb_ + (size_t)(8 + srow8) * 1536 + scol,                         \
             (char*)&lK[buf][0] + (wid << 11) + 1024);                        \
    gl_lds16(vb_ + (size_t)srow8 * 16384 + scol,                              \
             (char*)&lV[buf][0] + (wid << 11));                               \
    gl_lds16(vb_ + (size_t)(8 + srow8) * 16384 + scol,                        \
             (char*)&lV[buf][0] + (wid << 11) + 1024);                        \
  } while (0)

  // swizzled LDS read index (u16): row*64 + ((slot ^ (row&7)) * 8)
#define SWZ(row, slot) (((row) << 6) + ((((slot) ^ ((row) & 7))) << 3))

  // Q fragments (B-operand); Q pre-scaled by 1/8
  bf16v8 qf[2][2];
#pragma unroll
  for (int qt = 0; qt < 2; ++qt)
#pragma unroll
    for (int kk = 0; kk < 2; ++kk)
      qf[qt][kk] = *(const bf16v8*)(Qh + (size_t)(qw + qt * 16 + l16) * 768 +
                                    kk * 32 + g * 8);

  f32x4 po[2][4];
#pragma unroll
  for (int qt = 0; qt < 2; ++qt)
#pragma unroll
    for (int ht = 0; ht < 4; ++ht) po[qt][ht] = (f32x4)0.f;
  float m[2] = {-3e38f, -3e38f};
  float l[2] = {0.f, 0.f};

  FSTAGE(0, 0);
  __syncthreads();

  for (int c = 0; c < nch; ++c) {
    const int cur = c & 1;
    const int kv0 = c << 6;
    if (c + 1 < nch) FSTAGE(cur ^ 1, c + 1);

    if (kv0 <= qw + 31) {   // wave has unmasked rows in this chunk
      // K fragments (A-operand) from LDS
      bf16v8 kf[4][2];
#pragma unroll
      for (int kvt = 0; kvt < 4; ++kvt)
#pragma unroll
        for (int kk = 0; kk < 2; ++kk)
          kf[kvt][kk] =
              *(const bf16v8*)&lK[cur][SWZ(kvt * 16 + l16, kk * 4 + g)];
      // S^T[kv][q]
      f32x4 s[4][2];
#pragma unroll
      for (int kvt = 0; kvt < 4; ++kvt)
#pragma unroll
        for (int qt = 0; qt < 2; ++qt) {
          f32x4 a = (f32x4)0.f;
          a = mfma16(kf[kvt][0], qf[qt][0], a);
          a = mfma16(kf[kvt][1], qf[qt][1], a);
          s[kvt][qt] = a;
        }
      // V^T fragments (B-operand) from LDS
      bf16v8 vf[4][2];
#pragma unroll
      for (int ht = 0; ht < 4; ++ht)
#pragma unroll
        for (int kk = 0; kk < 2; ++kk)
          vf[ht][kk] =
              *(const bf16v8*)&lV[cur][SWZ(ht * 16 + l16, kk * 4 + g)];
      if (kv0 + 63 > qw) {  // boundary: causal mask kv > q
#pragma unroll
        for (int kvt = 0; kvt < 4; ++kvt) {
          const int kv = kv0 + kvt * 16 + g * 4;
#pragma unroll
          for (int qt = 0; qt < 2; ++qt) {
            const int qq = qw + qt * 16 + l16;
#pragma unroll
            for (int r = 0; r < 4; ++r)
              if (kv + r > qq) s[kvt][qt][r] = -3e38f;
          }
        }
      }
      // online softmax: q-row = l16 lane-local over kv
#pragma unroll
      for (int qt = 0; qt < 2; ++qt) {
        float cm = s[0][qt][0];
#pragma unroll
        for (int kvt = 0; kvt < 4; ++kvt)
#pragma unroll
          for (int r = 0; r < 4; ++r) cm = fmaxf(cm, s[kvt][qt][r]);
        cm = fmaxf(cm, __shfl_xor(cm, 16));
        cm = fmaxf(cm, __shfl_xor(cm, 32));
        const float mn = fmaxf(m[qt], cm);
        const float scl = __expf(m[qt] - mn);
        m[qt] = mn;
        float rs = 0.f;
#pragma unroll
        for (int kvt = 0; kvt < 4; ++kvt) {
          u16x4 pw;
#pragma unroll
          for (int r = 0; r < 4; ++r) {
            const float p = __expf(s[kvt][qt][r] - mn);
            rs += p;
            pw[r] = f2b(p);
          }
          *(u16x4*)&myP[(qt * 16 + l16) * 72 + kvt * 16 + g * 4] = pw;
        }
        rs += __shfl_xor(rs, 16);
        rs += __shfl_xor(rs, 32);
        l[qt] = l[qt] * scl + rs;
#pragma unroll
        for (int r = 0; r < 4; ++r) {
          const float sr = __shfl(scl, g * 4 + r);
#pragma unroll
          for (int ht = 0; ht < 4; ++ht) po[qt][ht][r] *= sr;
        }
      }
      // P fragments (A-operand) from wave-private LDS
      bf16v8 pa[2][2];
#pragma unroll
      for (int mt = 0; mt < 2; ++mt)
#pragma unroll
        for (int kk = 0; kk < 2; ++kk)
          pa[mt][kk] = *(const bf16v8*)&myP[(mt * 16 + l16) * 72 +
                                            kk * 32 + g * 8];
#pragma unroll
      for (int ht = 0; ht < 4; ++ht)
#pragma unroll
        for (int mt = 0; mt < 2; ++mt) {
          po[mt][ht] = mfma16(pa[mt][0], vf[ht][0], po[mt][ht]);
          po[mt][ht] = mfma16(pa[mt][1], vf[ht][1], po[mt][ht]);
        }
    }
    __syncthreads();
  }
#undef FSTAGE
#undef SWZ

  // epilogue: broadcast l to accumulator layout, divide, store
#pragma unroll
  for (int qt = 0; qt < 2; ++qt) {
#pragma unroll
    for (int r = 0; r < 4; ++r) {
      const float lr = __shfl(l[qt], g * 4 + r);
      const float inv = 1.f / lr;
      const int qq = qw + qt * 16 + g * 4 + r;
#pragma unroll
      for (int ht = 0; ht < 4; ++ht)
        Zh[(size_t)qq * 768 + ht * 16 + l16] = f2b(po[qt][ht][r] * inv);
    }
  }
}

// ---------------------------------------------------------------- launch ----
extern "C" void kernel_launch(void* const* d_in, const int* in_sizes, int n_in,
                              void* d_out, int out_size, void* d_ws,
                              size_t ws_size, hipStream_t stream) {
  const float* x  = (const float*)d_in[0];
  const float* wq = (const float*)d_in[1];
  const float* wk = (const float*)d_in[2];
  const float* wv = (const float*)d_in[3];
  const float* wo = (const float*)d_in[4];
  const float* bq = (const float*)d_in[5];
  const float* bk = (const float*)d_in[6];
  const float* bv = (const float*)d_in[7];
  const float* bo = (const float*)d_in[8];
  float* out = (float*)d_out;

  char* ws = (char*)d_ws;
  u16* Xb  = (u16*)ws; ws += 12582912;   // [8192][768] bf16
  u16* WqT = (u16*)ws; ws += 1179648;    // [768][768] bf16 (B^T layout)
  u16* WkT = (u16*)ws; ws += 1179648;
  u16* WvT = (u16*)ws; ws += 1179648;
  u16* WoT = (u16*)ws; ws += 1179648;
  u16* Qb  = (u16*)ws; ws += 12582912;   // [8192][768]
  u16* Kb  = (u16*)ws; ws += 12582912;   // [8192][768]
  u16* Vtb = (u16*)ws; ws += 12582912;   // [768][8192]  (V transposed)
  u16* Zb  = (u16*)ws; ws += 12582912;   // [8192][768]

  pack_x_kernel<<<3072, 256, 0, stream>>>(x, Xb, 786432);
  pack_w_kernel<<<dim3(12, 1, 12), 256, 0, stream>>>(wq, WqT, 49152, 64, 49152, 768);
  pack_w_kernel<<<dim3(12, 1, 12), 256, 0, stream>>>(wk, WkT, 49152, 64, 49152, 768);
  pack_w_kernel<<<dim3(12, 1, 12), 256, 0, stream>>>(wv, WvT, 49152, 64, 49152, 768);
  pack_w_kernel<<<dim3(1, 12, 12), 256, 0, stream>>>(wo, WoT, 49152, 768, 64, 768);

  gemm_bt<0, 0><<<dim3(64, 6), 256, 0, stream>>>(Xb, WqT, Qb, bq, 0.125f, 768);
  gemm_bt<0, 0><<<dim3(64, 6), 256, 0, stream>>>(Xb, WkT, Kb, bk, 1.0f, 768);
  // V^T = (Wv^T) . X^T directly: A = WvT [768][768], Bt = Xb [8192][768]
  gemm_bt<0, 1><<<dim3(6, 64), 256, 0, stream>>>(WvT, Xb, Vtb, bv, 1.0f, 8192);

  flash3_kernel<<<dim3(768), 256, 0, stream>>>(Qb, Kb, Vtb, Zb);

  gemm_bt<1, 0><<<dim3(64, 6), 256, 0, stream>>>(Zb, WoT, out, bo, 1.0f, 768);
}